// Round 9
// baseline (8450.742 us; speedup 1.0000x reference)
//
#include <hip/hip_runtime.h>

#define NG 64
#define GSC 1024       // scatter grid blocks
#define NBK_MAX 1024   // max buckets (N <= 65536)

typedef __bf16 bf16x8 __attribute__((ext_vector_type(8)));
typedef float  f32x4  __attribute__((ext_vector_type(4)));

__device__ __forceinline__ ushort f2bf(float f) {
    unsigned int b = __float_as_uint(f);
    b += 0x7fffu + ((b >> 16) & 1u);   // RTNE
    return (ushort)(b >> 16);
}
__device__ __forceinline__ float bf2f(ushort u) {
    return __uint_as_float((unsigned int)u << 16);
}

// ---------------- pass A: per-block bucket counts (LDS histogram) ----------------
__global__ __launch_bounds__(256) void bucket_count(const int* __restrict__ dst, int E, int nbk,
                                                    int* __restrict__ cntA /* [GSC][nbk] */)
{
    __shared__ int h[NBK_MAX];
    for (int i = threadIdx.x; i < nbk; i += 256) h[i] = 0;
    __syncthreads();
    int chunk = (E + GSC - 1) / GSC;
    int i0 = blockIdx.x * chunk, i1 = min(E, i0 + chunk);
    for (int i = i0 + threadIdx.x; i < i1; i += 256)
        atomicAdd(&h[dst[i] >> 6], 1);
    __syncthreads();
    int* out = cntA + (size_t)blockIdx.x * nbk;
    for (int i = threadIdx.x; i < nbk; i += 256) out[i] = h[i];
}

// ---------------- scan over blocks per bucket: basesA[k][b] = excl prefix; btot[b] ----------------
__global__ __launch_bounds__(1024) void scan_blocks(const int* __restrict__ cntA, int nbk,
                                                    int* __restrict__ basesA, int* __restrict__ btot)
{
    int b = blockIdx.x;
    int t = threadIdx.x, lane = t & 63, wv = t >> 6;
    __shared__ int wsum[16];
    int v = cntA[(size_t)t * nbk + b];
    int x = v;
    #pragma unroll
    for (int off = 1; off < 64; off <<= 1) { int u = __shfl_up(x, off, 64); if (lane >= off) x += u; }
    if (lane == 63) wsum[wv] = x;
    __syncthreads();
    if (wv == 0 && lane < 16) {
        int w = wsum[lane];
        #pragma unroll
        for (int off = 1; off < 16; off <<= 1) { int u = __shfl_up(w, off, 64); if (lane >= off) w += u; }
        wsum[lane] = w;
    }
    __syncthreads();
    int incl = x + (wv > 0 ? wsum[wv - 1] : 0);
    basesA[(size_t)t * nbk + b] = incl - v;
    if (t == 1023) btot[b] = incl;
}

// ---------------- exclusive scan of bucket totals -> bbase[0..nbk] ----------------
__global__ __launch_bounds__(1024) void scan_buckets(const int* __restrict__ btot, int nbk,
                                                     int* __restrict__ bbase)
{
    int t = threadIdx.x, lane = t & 63, wv = t >> 6;
    __shared__ int wsum[16];
    int v = (t < nbk) ? btot[t] : 0;
    int x = v;
    #pragma unroll
    for (int off = 1; off < 64; off <<= 1) { int u = __shfl_up(x, off, 64); if (lane >= off) x += u; }
    if (lane == 63) wsum[wv] = x;
    __syncthreads();
    if (wv == 0 && lane < 16) {
        int w = wsum[lane];
        #pragma unroll
        for (int off = 1; off < 16; off <<= 1) { int u = __shfl_up(w, off, 64); if (lane >= off) w += u; }
        wsum[lane] = w;
    }
    __syncthreads();
    int incl = x + (wv > 0 ? wsum[wv - 1] : 0);
    if (t <= nbk) bbase[t] = incl - v;
}

// ---------------- pass B: scatter (src,dst) into bucket-grouped ebuf (LDS counters) ----------------
__global__ __launch_bounds__(256) void bucket_scatter(const int* __restrict__ src, const int* __restrict__ dst,
                                                      int E, int nbk,
                                                      const int* __restrict__ basesA, const int* __restrict__ bbase,
                                                      int2* __restrict__ ebuf)
{
    __shared__ int cur[NBK_MAX];
    const int* bs = basesA + (size_t)blockIdx.x * nbk;
    for (int i = threadIdx.x; i < nbk; i += 256) cur[i] = bbase[i] + bs[i];
    __syncthreads();
    int chunk = (E + GSC - 1) / GSC;
    int i0 = blockIdx.x * chunk, i1 = min(E, i0 + chunk);
    for (int i = i0 + threadIdx.x; i < i1; i += 256) {
        int d = dst[i];
        int pos = atomicAdd(&cur[d >> 6], 1);
        ebuf[pos] = make_int2(src[i], d);
    }
}

// ---------------- bucket mean-aggregation: LDS f32 accumulate over 64 dst rows ----------------
__global__ __launch_bounds__(256) void bucketagg(const ushort* __restrict__ xb,
                                                 const int2* __restrict__ ebuf,
                                                 const int* __restrict__ bbase,
                                                 int M, ushort* __restrict__ mean)
{
    __shared__ float acc[64 * 128];   // 32 KB
    __shared__ int hdeg[64];
    int t = threadIdx.x, lane = t & 63, wave = t >> 6;
    for (int i = t; i < 64 * 128; i += 256) acc[i] = 0.f;
    if (t < 64) hdeg[t] = 0;
    __syncthreads();

    int e0 = bbase[blockIdx.x], e1 = bbase[blockIdx.x + 1];
    int cnt = e1 - e0;
    int per = (cnt + 3) >> 2;
    int we0 = e0 + wave * per;
    int we1 = min(e1, we0 + per);

    int e = we0;
    for (; e + 8 <= we1; e += 8) {
        int2 p0 = ebuf[e+0], p1 = ebuf[e+1], p2 = ebuf[e+2], p3 = ebuf[e+3];
        int2 p4 = ebuf[e+4], p5 = ebuf[e+5], p6 = ebuf[e+6], p7 = ebuf[e+7];
        float l0 = bf2f(xb[(size_t)p0.x * 128 + lane]), h0 = bf2f(xb[(size_t)p0.x * 128 + 64 + lane]);
        float l1 = bf2f(xb[(size_t)p1.x * 128 + lane]), h1 = bf2f(xb[(size_t)p1.x * 128 + 64 + lane]);
        float l2 = bf2f(xb[(size_t)p2.x * 128 + lane]), h2 = bf2f(xb[(size_t)p2.x * 128 + 64 + lane]);
        float l3 = bf2f(xb[(size_t)p3.x * 128 + lane]), h3 = bf2f(xb[(size_t)p3.x * 128 + 64 + lane]);
        float l4 = bf2f(xb[(size_t)p4.x * 128 + lane]), h4 = bf2f(xb[(size_t)p4.x * 128 + 64 + lane]);
        float l5 = bf2f(xb[(size_t)p5.x * 128 + lane]), h5 = bf2f(xb[(size_t)p5.x * 128 + 64 + lane]);
        float l6 = bf2f(xb[(size_t)p6.x * 128 + lane]), h6 = bf2f(xb[(size_t)p6.x * 128 + 64 + lane]);
        float l7 = bf2f(xb[(size_t)p7.x * 128 + lane]), h7 = bf2f(xb[(size_t)p7.x * 128 + 64 + lane]);
        int d0 = (p0.y & 63) * 128, d1 = (p1.y & 63) * 128, d2 = (p2.y & 63) * 128, d3 = (p3.y & 63) * 128;
        int d4 = (p4.y & 63) * 128, d5 = (p5.y & 63) * 128, d6 = (p6.y & 63) * 128, d7 = (p7.y & 63) * 128;
        atomicAdd(&acc[d0 + lane], l0); atomicAdd(&acc[d0 + 64 + lane], h0);
        atomicAdd(&acc[d1 + lane], l1); atomicAdd(&acc[d1 + 64 + lane], h1);
        atomicAdd(&acc[d2 + lane], l2); atomicAdd(&acc[d2 + 64 + lane], h2);
        atomicAdd(&acc[d3 + lane], l3); atomicAdd(&acc[d3 + 64 + lane], h3);
        atomicAdd(&acc[d4 + lane], l4); atomicAdd(&acc[d4 + 64 + lane], h4);
        atomicAdd(&acc[d5 + lane], l5); atomicAdd(&acc[d5 + 64 + lane], h5);
        atomicAdd(&acc[d6 + lane], l6); atomicAdd(&acc[d6 + 64 + lane], h6);
        atomicAdd(&acc[d7 + lane], l7); atomicAdd(&acc[d7 + 64 + lane], h7);
        if (lane == 0) {
            atomicAdd(&hdeg[p0.y & 63], 1); atomicAdd(&hdeg[p1.y & 63], 1);
            atomicAdd(&hdeg[p2.y & 63], 1); atomicAdd(&hdeg[p3.y & 63], 1);
            atomicAdd(&hdeg[p4.y & 63], 1); atomicAdd(&hdeg[p5.y & 63], 1);
            atomicAdd(&hdeg[p6.y & 63], 1); atomicAdd(&hdeg[p7.y & 63], 1);
        }
    }
    for (; e < we1; ++e) {
        int2 p = ebuf[e];
        float lo = bf2f(xb[(size_t)p.x * 128 + lane]);
        float hi = bf2f(xb[(size_t)p.x * 128 + 64 + lane]);
        int dd = (p.y & 63) * 128;
        atomicAdd(&acc[dd + lane], lo);
        atomicAdd(&acc[dd + 64 + lane], hi);
        if (lane == 0) atomicAdd(&hdeg[p.y & 63], 1);
    }
    __syncthreads();

    for (int i = t; i < 64 * 64; i += 256) {
        int dl = i >> 6, cp = i & 63;
        int row = (blockIdx.x << 6) + dl;
        if (row < M) {
            int dg = hdeg[dl];
            float sc = 1.f / (float)(dg > 1 ? dg : 1);
            unsigned int pk = (unsigned int)f2bf(acc[dl * 128 + cp * 2] * sc)
                            | ((unsigned int)f2bf(acc[dl * 128 + cp * 2 + 1] * sc) << 16);
            ((unsigned int*)mean)[(size_t)row * 64 + cp] = pk;
        }
    }
}

// ---------------- elementwise add (bias sums) ----------------
__global__ void add2_kernel(const float* __restrict__ a, const float* __restrict__ b,
                            float* __restrict__ o, int n) {
    int i = blockIdx.x * blockDim.x + threadIdx.x;
    if (i < n) o[i] = a[i] + b[i];
}

// ---------------- f32 -> bf16 conversion ----------------
__global__ void cvt_kernel(const float* __restrict__ x, ushort* __restrict__ o, int n4) {
    int i = blockIdx.x * blockDim.x + threadIdx.x;
    if (i >= n4) return;
    float4 v = ((const float4*)x)[i];
    ushort4 r;
    r.x = f2bf(v.x); r.y = f2bf(v.y); r.z = f2bf(v.z); r.w = f2bf(v.w);
    ((ushort4*)o)[i] = r;
}

// ---------------- weight prep: Wt[n][k] = bf16(Wa[k][n] (+Wb[k][n])) ----------------
__global__ void wprep_kernel(
    const float* __restrict__ Wa0, const float* __restrict__ Wb0, ushort* __restrict__ Wt0,
    const float* __restrict__ Wa1, ushort* __restrict__ Wt1,
    const float* __restrict__ Wa2, ushort* __restrict__ Wt2,
    const float* __restrict__ Wa3, ushort* __restrict__ Wt3,
    const float* __restrict__ Wa4, ushort* __restrict__ Wt4)
{
    const float* Wa; const float* Wb = nullptr; ushort* Wt;
    switch (blockIdx.x) {
        case 0: Wa = Wa0; Wb = Wb0; Wt = Wt0; break;
        case 1: Wa = Wa1; Wt = Wt1; break;
        case 2: Wa = Wa2; Wt = Wt2; break;
        case 3: Wa = Wa3; Wt = Wt3; break;
        default: Wa = Wa4; Wt = Wt4; break;
    }
    for (int idx = threadIdx.x; idx < 128 * 128; idx += 256) {
        int n = idx >> 7, k = idx & 127;
        float v = Wa[k * 128 + n];
        if (Wb) v += Wb[k * 128 + n];
        Wt[idx] = f2bf(v);
    }
}

// ---------------- graph boundaries via binary search (batch is sorted) ----------------
__global__ void bounds_kernel(const int* __restrict__ bu, int nu,
                              const int* __restrict__ bd, int nd,
                              int* __restrict__ bndu, int* __restrict__ bndd)
{
    const int* b = blockIdx.x == 0 ? bu : bd;
    int        n = blockIdx.x == 0 ? nu : nd;
    int*       o = blockIdx.x == 0 ? bndu : bndd;
    int g = threadIdx.x;
    if (g > NG) return;
    int lo = 0, hi = n;
    while (lo < hi) { int m = (lo + hi) >> 1; if (b[m] < g) lo = m + 1; else hi = m; }
    o[g] = lo;
}

// ---------------- MFMA multi-term GEMM: C = relu(sum A_t @ W_t + bias) -> bf16 ----------------
template<int NA>
__global__ __launch_bounds__(256) void gemm_mfma(
    const ushort* __restrict__ A0, const ushort* __restrict__ A1, const ushort* __restrict__ A2,
    const ushort* __restrict__ Wt0, const ushort* __restrict__ Wt1, const ushort* __restrict__ Wt2,
    int M, const float* __restrict__ bias, ushort* __restrict__ C)
{
    int wave = threadIdx.x >> 6, lane = threadIdx.x & 63;
    int row0 = blockIdx.x * 64 + wave * 16;
    int r  = lane & 15;
    int kg = lane >> 4;
    f32x4 acc[8];
    #pragma unroll
    for (int nt = 0; nt < 8; ++nt) acc[nt] = (f32x4){0.f, 0.f, 0.f, 0.f};

    int arow = row0 + r;
    int arow_c = arow < M ? arow : 0;
    #pragma unroll
    for (int term = 0; term < NA; ++term) {
        const ushort* A  = (term == 0) ? A0  : (term == 1 ? A1  : A2);
        const ushort* Wt = (term == 0) ? Wt0 : (term == 1 ? Wt1 : Wt2);
        #pragma unroll
        for (int kk = 0; kk < 4; ++kk) {
            bf16x8 a = *(const bf16x8*)&A[(size_t)arow_c * 128 + kk * 32 + kg * 8];
            #pragma unroll
            for (int nt = 0; nt < 8; ++nt) {
                bf16x8 b = *(const bf16x8*)&Wt[(size_t)(nt * 16 + r) * 128 + kk * 32 + kg * 8];
                acc[nt] = __builtin_amdgcn_mfma_f32_16x16x32_bf16(a, b, acc[nt], 0, 0, 0);
            }
        }
    }

    #pragma unroll
    for (int nt = 0; nt < 8; ++nt) {
        int col = nt * 16 + r;
        float bv = bias[col];
        #pragma unroll
        for (int j = 0; j < 4; ++j) {
            int orow = row0 + kg * 4 + j;
            if (orow < M) {
                float v = fmaxf(acc[nt][j] + bv, 0.f);
                C[(size_t)orow * 128 + col] = f2bf(v);
            }
        }
    }
}

// ---------------- 5-way per-graph row-sum pool over bf16 rows (batch sorted) ----------------
__global__ __launch_bounds__(256) void pool5_kernel(
    const ushort* __restrict__ m2du, const ushort* __restrict__ m2uu, const ushort* __restrict__ m2ud,
    const ushort* __restrict__ u1b,  const ushort* __restrict__ d1b,
    const int* __restrict__ bndu, const int* __restrict__ bndd,
    float* __restrict__ pmdu, float* __restrict__ pmuu, float* __restrict__ pmud,
    float* __restrict__ pu1, float* __restrict__ pd1)
{
    const ushort* xb; const int* bnd; float* pool;
    switch (blockIdx.y) {
        case 0: xb = m2du; bnd = bndu; pool = pmdu; break;
        case 1: xb = m2uu; bnd = bndu; pool = pmuu; break;
        case 2: xb = m2ud; bnd = bndd; pool = pmud; break;
        case 3: xb = u1b;  bnd = bndu; pool = pu1;  break;
        default: xb = d1b; bnd = bndd; pool = pd1;  break;
    }
    int g = blockIdx.x;
    int lo = bnd[g], hi = bnd[g + 1];
    int c2 = threadIdx.x & 63, half = threadIdx.x >> 6;
    float sx = 0.f, sy = 0.f;
    for (int r = lo + half; r < hi; r += 4) {
        unsigned int v = *(const unsigned int*)&xb[(size_t)r * 128 + c2 * 2];
        sx += __uint_as_float(v << 16);
        sy += __uint_as_float(v & 0xffff0000u);
    }
    __shared__ float ls[256 * 2];
    ls[threadIdx.x * 2]     = sx;
    ls[threadIdx.x * 2 + 1] = sy;
    __syncthreads();
    if (half == 0) {
        float ox = ls[c2 * 2] + ls[(64 + c2) * 2] + ls[(128 + c2) * 2] + ls[(192 + c2) * 2];
        float oy = ls[c2 * 2 + 1] + ls[(64 + c2) * 2 + 1] + ls[(128 + c2) * 2 + 1] + ls[(192 + c2) * 2 + 1];
        pool[g * 128 + c2 * 2]     = ox;
        pool[g * 128 + c2 * 2 + 1] = oy;
    }
}

// ---------------- final: layer-2 matmuls at graph level + MLP + log_softmax ----------------
__global__ __launch_bounds__(128) void final_kernel(
    const float* __restrict__ pmdu, const float* __restrict__ pmuu, const float* __restrict__ pmud,
    const float* __restrict__ pu1,  const float* __restrict__ pd1,
    const int* __restrict__ bndu, const int* __restrict__ bndd,
    const float* __restrict__ Wl2_du, const float* __restrict__ bl2_du, const float* __restrict__ Wr2_du,
    const float* __restrict__ Wl2_uu, const float* __restrict__ bl2_uu, const float* __restrict__ Wr2_uu,
    const float* __restrict__ Wl2_ud, const float* __restrict__ bl2_ud, const float* __restrict__ Wr2_ud,
    const float* __restrict__ W1, const float* __restrict__ b1,
    const float* __restrict__ W2, const float* __restrict__ b2,
    float* __restrict__ out)
{
    int g = blockIdx.x, t = threadIdx.x;
    __shared__ float smdu[128], smuu[128], smud[128], su1[128], sd1[128];
    __shared__ float xrow[256], h[128], lg[2];
    smdu[t] = pmdu[g * 128 + t];
    smuu[t] = pmuu[g * 128 + t];
    smud[t] = pmud[g * 128 + t];
    su1[t]  = pu1[g * 128 + t];
    sd1[t]  = pd1[g * 128 + t];
    __syncthreads();
    float ncu = (float)(bndu[g + 1] - bndu[g]);
    float ncd = (float)(bndd[g + 1] - bndd[g]);
    float cu = ncu > 1.f ? ncu : 1.f, cd = ncd > 1.f ? ncd : 1.f;
    float accu = ncu * (bl2_du[t] + bl2_uu[t]);
    float accd = ncd * bl2_ud[t];
    for (int k = 0; k < 128; ++k) {
        accu += smdu[k] * Wl2_du[k * 128 + t]
              + smuu[k] * Wl2_uu[k * 128 + t]
              + su1[k]  * (Wr2_du[k * 128 + t] + Wr2_uu[k * 128 + t]);
        accd += smud[k] * Wl2_ud[k * 128 + t]
              + sd1[k]  * Wr2_ud[k * 128 + t];
    }
    xrow[t]       = accu / cu;
    xrow[128 + t] = accd / cd;
    __syncthreads();
    float hh = b1[t];
    for (int k = 0; k < 256; ++k) hh += xrow[k] * W1[k * 128 + t];
    h[t] = fmaxf(hh, 0.f);
    __syncthreads();
    if (t < 2) {
        float l = b2[t];
        for (int k = 0; k < 128; ++k) l += h[k] * W2[k * 2 + t];
        lg[t] = l;
    }
    __syncthreads();
    if (t == 0) {
        float m = fmaxf(lg[0], lg[1]);
        float lse = m + logf(expf(lg[0] - m) + expf(lg[1] - m));
        out[g * 2 + 0] = lg[0] - lse;
        out[g * 2 + 1] = lg[1] - lse;
    }
}

extern "C" void kernel_launch(void* const* d_in, const int* in_sizes, int n_in,
                              void* d_out, int out_size, void* d_ws, size_t ws_size,
                              hipStream_t stream)
{
    const float* x_user = (const float*)d_in[0];
    const float* x_drug = (const float*)d_in[1];
    const int* ei_ud = (const int*)d_in[2];
    const int* ei_du = (const int*)d_in[3];
    const int* ei_uu = (const int*)d_in[4];
    const int* batch_u = (const int*)d_in[5];
    const int* batch_d = (const int*)d_in[6];
    const float* Wl1_ud = (const float*)d_in[7];  const float* bl1_ud = (const float*)d_in[8];  const float* Wr1_ud = (const float*)d_in[9];
    const float* Wl1_du = (const float*)d_in[10]; const float* bl1_du = (const float*)d_in[11]; const float* Wr1_du = (const float*)d_in[12];
    const float* Wl1_uu = (const float*)d_in[13]; const float* bl1_uu = (const float*)d_in[14]; const float* Wr1_uu = (const float*)d_in[15];
    const float* Wl2_ud = (const float*)d_in[16]; const float* bl2_ud = (const float*)d_in[17]; const float* Wr2_ud = (const float*)d_in[18];
    const float* Wl2_du = (const float*)d_in[19]; const float* bl2_du = (const float*)d_in[20]; const float* Wr2_du = (const float*)d_in[21];
    const float* Wl2_uu = (const float*)d_in[22]; const float* bl2_uu = (const float*)d_in[23]; const float* Wr2_uu = (const float*)d_in[24];
    const float* W1 = (const float*)d_in[25]; const float* b1 = (const float*)d_in[26];
    const float* W2 = (const float*)d_in[27]; const float* b2 = (const float*)d_in[28];
    (void)n_in; (void)out_size; (void)ws_size;

    const int Nu = in_sizes[0] / 128;
    const int Nd = in_sizes[1] / 128;
    const int E_ud = in_sizes[2] / 2;
    const int E_du = in_sizes[3] / 2;
    const int E_uu = in_sizes[4] / 2;
    const int nbk_u = (Nu + 63) >> 6;   // buckets over user-dst space
    const int nbk_d = (Nd + 63) >> 6;   // buckets over drug-dst space

    char* ws = (char*)d_ws;
    size_t off = 0;
    auto alloc = [&](size_t bytes) -> void* {
        void* p = ws + off;
        off = (off + bytes + 255) & ~(size_t)255;
        return p;
    };
    int2* ebuf_ud = (int2*)alloc((size_t)E_ud * 8);
    int2* ebuf_du = (int2*)alloc((size_t)E_du * 8);
    int2* ebuf_uu = (int2*)alloc((size_t)E_uu * 8);
    int* cntA   = (int*)alloc((size_t)GSC * NBK_MAX * 4);   // reused per type
    int* basesA = (int*)alloc((size_t)GSC * NBK_MAX * 4);   // reused per type
    int* btot   = (int*)alloc((size_t)NBK_MAX * 4);
    int* bbase_ud = (int*)alloc((size_t)(NBK_MAX + 1) * 4);
    int* bbase_du = (int*)alloc((size_t)(NBK_MAX + 1) * 4);
    int* bbase_uu = (int*)alloc((size_t)(NBK_MAX + 1) * 4);
    ushort* xb_u = (ushort*)alloc((size_t)Nu * 128 * 2);
    ushort* xb_d = (ushort*)alloc((size_t)Nd * 128 * 2);
    ushort* mean_du = (ushort*)alloc((size_t)Nu * 128 * 2);   // layer-2 means overlay after gemms
    ushort* mean_uu = (ushort*)alloc((size_t)Nu * 128 * 2);
    ushort* mean_ud = (ushort*)alloc((size_t)Nd * 128 * 2);
    ushort* u1b = (ushort*)alloc((size_t)Nu * 128 * 2);
    ushort* d1b = (ushort*)alloc((size_t)Nd * 128 * 2);
    float* pmdu = (float*)alloc(NG * 128 * 4);
    float* pmuu = (float*)alloc(NG * 128 * 4);
    float* pmud = (float*)alloc(NG * 128 * 4);
    float* pu1  = (float*)alloc(NG * 128 * 4);
    float* pd1  = (float*)alloc(NG * 128 * 4);
    int* bnd_u = (int*)alloc((NG + 1) * 4);
    int* bnd_d = (int*)alloc((NG + 1) * 4);
    ushort* Wt_ru  = (ushort*)alloc(128 * 128 * 2);
    ushort* Wt_ldu = (ushort*)alloc(128 * 128 * 2);
    ushort* Wt_luu = (ushort*)alloc(128 * 128 * 2);
    ushort* Wt_rud = (ushort*)alloc(128 * 128 * 2);
    ushort* Wt_lud = (ushort*)alloc(128 * 128 * 2);
    float* b1s_u  = (float*)alloc(128 * 4);

    const int* dst_ud = ei_ud + E_ud;
    const int* dst_du = ei_du + E_du;
    const int* dst_uu = ei_uu + E_uu;

    // ---- bucket-grouped edge build (all atomics in LDS) ----
    bucket_count<<<GSC, 256, 0, stream>>>(dst_ud, E_ud, nbk_d, cntA);
    scan_blocks<<<nbk_d, 1024, 0, stream>>>(cntA, nbk_d, basesA, btot);
    scan_buckets<<<1, 1024, 0, stream>>>(btot, nbk_d, bbase_ud);
    bucket_scatter<<<GSC, 256, 0, stream>>>(ei_ud, dst_ud, E_ud, nbk_d, basesA, bbase_ud, ebuf_ud);

    bucket_count<<<GSC, 256, 0, stream>>>(dst_du, E_du, nbk_u, cntA);
    scan_blocks<<<nbk_u, 1024, 0, stream>>>(cntA, nbk_u, basesA, btot);
    scan_buckets<<<1, 1024, 0, stream>>>(btot, nbk_u, bbase_du);
    bucket_scatter<<<GSC, 256, 0, stream>>>(ei_du, dst_du, E_du, nbk_u, basesA, bbase_du, ebuf_du);

    bucket_count<<<GSC, 256, 0, stream>>>(dst_uu, E_uu, nbk_u, cntA);
    scan_blocks<<<nbk_u, 1024, 0, stream>>>(cntA, nbk_u, basesA, btot);
    scan_buckets<<<1, 1024, 0, stream>>>(btot, nbk_u, bbase_uu);
    bucket_scatter<<<GSC, 256, 0, stream>>>(ei_uu, dst_uu, E_uu, nbk_u, basesA, bbase_uu, ebuf_uu);

    // ---- graph boundaries, bf16 inputs, weight prep ----
    bounds_kernel<<<2, NG + 1, 0, stream>>>(batch_u, Nu, batch_d, Nd, bnd_u, bnd_d);
    cvt_kernel<<<(Nu * 32 + 255) / 256, 256, 0, stream>>>(x_user, xb_u, Nu * 32);
    cvt_kernel<<<(Nd * 32 + 255) / 256, 256, 0, stream>>>(x_drug, xb_d, Nd * 32);
    wprep_kernel<<<5, 256, 0, stream>>>(Wr1_du, Wr1_uu, Wt_ru,
                                        Wl1_du, Wt_ldu, Wl1_uu, Wt_luu,
                                        Wr1_ud, Wt_rud, Wl1_ud, Wt_lud);
    add2_kernel<<<1, 128, 0, stream>>>(bl1_du, bl1_uu, b1s_u, 128);

    // ---- layer-1 mean aggregation (bucket LDS accumulate) ----
    bucketagg<<<nbk_u, 256, 0, stream>>>(xb_d, ebuf_du, bbase_du, Nu, mean_du);
    bucketagg<<<nbk_u, 256, 0, stream>>>(xb_u, ebuf_uu, bbase_uu, Nu, mean_uu);
    bucketagg<<<nbk_d, 256, 0, stream>>>(xb_u, ebuf_ud, bbase_ud, Nd, mean_ud);

    // ---- layer-1 MFMA GEMMs -> bf16 ----
    gemm_mfma<3><<<(Nu + 63) / 64, 256, 0, stream>>>(xb_u, mean_du, mean_uu,
                                                     Wt_ru, Wt_ldu, Wt_luu, Nu, b1s_u, u1b);
    gemm_mfma<2><<<(Nd + 63) / 64, 256, 0, stream>>>(xb_d, mean_ud, nullptr,
                                                     Wt_rud, Wt_lud, nullptr, Nd, bl1_ud, d1b);

    // ---- layer-2 mean aggregation (same ebufs, x = layer-1 out; overlay dead mean buffers) ----
    bucketagg<<<nbk_u, 256, 0, stream>>>(d1b, ebuf_du, bbase_du, Nu, mean_du);
    bucketagg<<<nbk_u, 256, 0, stream>>>(u1b, ebuf_uu, bbase_uu, Nu, mean_uu);
    bucketagg<<<nbk_d, 256, 0, stream>>>(u1b, ebuf_ud, bbase_ud, Nd, mean_ud);

    // ---- all 5 per-graph pools (direct store) ----
    pool5_kernel<<<dim3(NG, 5), 256, 0, stream>>>(mean_du, mean_uu, mean_ud, u1b, d1b,
                                                  bnd_u, bnd_d, pmdu, pmuu, pmud, pu1, pd1);

    // ---- graph-level layer-2 matmuls + MLP + log_softmax ----
    final_kernel<<<NG, 128, 0, stream>>>(pmdu, pmuu, pmud, pu1, pd1, bnd_u, bnd_d,
                                         Wl2_du, bl2_du, Wr2_du,
                                         Wl2_uu, bl2_uu, Wr2_uu,
                                         Wl2_ud, bl2_ud, Wr2_ud,
                                         W1, b1, W2, b2, (float*)d_out);
}

// Round 10
// 741.348 us; speedup vs baseline: 11.3992x; 11.3992x over previous
//
#include <hip/hip_runtime.h>

#define NG 64
#define REP 8          // aggpool replicas
#define GSC 512        // scatter grid blocks
#define NBK_MAX 1024   // max buckets (N <= 65536)

typedef __bf16 bf16x8 __attribute__((ext_vector_type(8)));
typedef float  f32x4  __attribute__((ext_vector_type(4)));

__device__ __forceinline__ ushort f2bf(float f) {
    unsigned int b = __float_as_uint(f);
    b += 0x7fffu + ((b >> 16) & 1u);   // RTNE
    return (ushort)(b >> 16);
}

// ---------------- pass A: per-block bucket counts (LDS int hist) ----------------
__global__ __launch_bounds__(256) void bucket_count(const int* __restrict__ dst, int E, int nbk,
                                                    int* __restrict__ cntA /* [nbk][GSC] */)
{
    __shared__ int h[NBK_MAX];
    for (int i = threadIdx.x; i < nbk; i += 256) h[i] = 0;
    __syncthreads();
    int chunk = (E + GSC - 1) / GSC;
    int i0 = blockIdx.x * chunk, i1 = min(E, i0 + chunk);
    for (int i = i0 + threadIdx.x; i < i1; i += 256)
        atomicAdd(&h[dst[i] >> 6], 1);
    __syncthreads();
    for (int i = threadIdx.x; i < nbk; i += 256)
        cntA[(size_t)i * GSC + blockIdx.x] = h[i];
}

// ---------------- scan over blocks per bucket (coalesced reads) ----------------
__global__ __launch_bounds__(GSC) void scan_blocks(const int* __restrict__ cntA, int nbk,
                                                   int* __restrict__ basesA, int* __restrict__ btot)
{
    int b = blockIdx.x;
    int t = threadIdx.x, lane = t & 63, wv = t >> 6;   // 8 waves
    __shared__ int wsum[8];
    int v = cntA[(size_t)b * GSC + t];
    int x = v;
    #pragma unroll
    for (int off = 1; off < 64; off <<= 1) { int u = __shfl_up(x, off, 64); if (lane >= off) x += u; }
    if (lane == 63) wsum[wv] = x;
    __syncthreads();
    if (wv == 0 && lane < 8) {
        int w = wsum[lane];
        #pragma unroll
        for (int off = 1; off < 8; off <<= 1) { int u = __shfl_up(w, off, 64); if (lane >= off) w += u; }
        wsum[lane] = w;
    }
    __syncthreads();
    int incl = x + (wv > 0 ? wsum[wv - 1] : 0);
    basesA[(size_t)b * GSC + t] = incl - v;
    if (t == GSC - 1) btot[b] = incl;
}

// ---------------- exclusive scan of bucket totals -> bbase[0..nbk] ----------------
__global__ __launch_bounds__(1024) void scan_buckets(const int* __restrict__ btot, int nbk,
                                                     int* __restrict__ bbase)
{
    int t = threadIdx.x, lane = t & 63, wv = t >> 6;
    __shared__ int wsum[16];
    int v = (t < nbk) ? btot[t] : 0;
    int x = v;
    #pragma unroll
    for (int off = 1; off < 64; off <<= 1) { int u = __shfl_up(x, off, 64); if (lane >= off) x += u; }
    if (lane == 63) wsum[wv] = x;
    __syncthreads();
    if (wv == 0 && lane < 16) {
        int w = wsum[lane];
        #pragma unroll
        for (int off = 1; off < 16; off <<= 1) { int u = __shfl_up(w, off, 64); if (lane >= off) w += u; }
        wsum[lane] = w;
    }
    __syncthreads();
    int incl = x + (wv > 0 ? wsum[wv - 1] : 0);
    if (t <= nbk) bbase[t] = incl - v;
}

// ---------------- pass B: scatter (src,dst) into bucket-grouped ebuf (LDS cursors) ----------------
__global__ __launch_bounds__(256) void bucket_scatter(const int* __restrict__ src, const int* __restrict__ dst,
                                                      int E, int nbk,
                                                      const int* __restrict__ basesA, const int* __restrict__ bbase,
                                                      int2* __restrict__ ebuf)
{
    __shared__ int cur[NBK_MAX];
    for (int i = threadIdx.x; i < nbk; i += 256)
        cur[i] = bbase[i] + basesA[(size_t)i * GSC + blockIdx.x];
    __syncthreads();
    int chunk = (E + GSC - 1) / GSC;
    int i0 = blockIdx.x * chunk, i1 = min(E, i0 + chunk);
    for (int i = i0 + threadIdx.x; i < i1; i += 256) {
        int d = dst[i];
        int pos = atomicAdd(&cur[d >> 6], 1);
        ebuf[pos] = make_int2(src[i], d);
    }
}

// ---------------- per-bucket: exact CSR from bucket-grouped edges (LDS 64-bin) ----------------
__global__ __launch_bounds__(256) void csrify_kernel(const int2* __restrict__ ebuf,
                                                     const int* __restrict__ bbase,
                                                     int M, int E,
                                                     int* __restrict__ rp, int* __restrict__ csr)
{
    __shared__ int hist[64], cur[64];
    int t = threadIdx.x;
    if (t < 64) hist[t] = 0;
    __syncthreads();
    int e0 = bbase[blockIdx.x], e1 = bbase[blockIdx.x + 1];
    for (int e = e0 + t; e < e1; e += 256)
        atomicAdd(&hist[ebuf[e].y & 63], 1);
    __syncthreads();
    if (t < 64) {
        int x = hist[t];
        #pragma unroll
        for (int off = 1; off < 64; off <<= 1) { int u = __shfl_up(x, off, 64); if (t >= off) x += u; }
        int ex = x - hist[t];
        cur[t] = ex;
        int row = (blockIdx.x << 6) + t;
        if (row < M) rp[row] = e0 + ex;
    }
    if (blockIdx.x == 0 && t == 0) rp[M] = E;
    __syncthreads();
    for (int e = e0 + t; e < e1; e += 256) {
        int2 p = ebuf[e];
        int pos = atomicAdd(&cur[p.y & 63], 1);
        csr[e0 + pos] = p.x;
    }
}

// ---------------- elementwise add (bias sums) ----------------
__global__ void add2_kernel(const float* __restrict__ a, const float* __restrict__ b,
                            float* __restrict__ o, int n) {
    int i = blockIdx.x * blockDim.x + threadIdx.x;
    if (i < n) o[i] = a[i] + b[i];
}

// ---------------- f32 -> bf16 conversion ----------------
__global__ void cvt_kernel(const float* __restrict__ x, ushort* __restrict__ o, int n4) {
    int i = blockIdx.x * blockDim.x + threadIdx.x;
    if (i >= n4) return;
    float4 v = ((const float4*)x)[i];
    ushort4 r;
    r.x = f2bf(v.x); r.y = f2bf(v.y); r.z = f2bf(v.z); r.w = f2bf(v.w);
    ((ushort4*)o)[i] = r;
}

// ---------------- weight prep: Wt[n][k] = bf16(Wa[k][n] (+Wb[k][n])) ----------------
__global__ void wprep_kernel(
    const float* __restrict__ Wa0, const float* __restrict__ Wb0, ushort* __restrict__ Wt0,
    const float* __restrict__ Wa1, ushort* __restrict__ Wt1,
    const float* __restrict__ Wa2, ushort* __restrict__ Wt2,
    const float* __restrict__ Wa3, ushort* __restrict__ Wt3,
    const float* __restrict__ Wa4, ushort* __restrict__ Wt4)
{
    const float* Wa; const float* Wb = nullptr; ushort* Wt;
    switch (blockIdx.x) {
        case 0: Wa = Wa0; Wb = Wb0; Wt = Wt0; break;
        case 1: Wa = Wa1; Wt = Wt1; break;
        case 2: Wa = Wa2; Wt = Wt2; break;
        case 3: Wa = Wa3; Wt = Wt3; break;
        default: Wa = Wa4; Wt = Wt4; break;
    }
    for (int idx = threadIdx.x; idx < 128 * 128; idx += 256) {
        int n = idx >> 7, k = idx & 127;
        float v = Wa[k * 128 + n];
        if (Wb) v += Wb[k * 128 + n];
        Wt[idx] = f2bf(v);
    }
}

// ---------------- graph boundaries via binary search (batch is sorted) ----------------
__global__ void bounds_kernel(const int* __restrict__ bu, int nu,
                              const int* __restrict__ bd, int nd,
                              int* __restrict__ bndu, int* __restrict__ bndd)
{
    const int* b = blockIdx.x == 0 ? bu : bd;
    int        n = blockIdx.x == 0 ? nu : nd;
    int*       o = blockIdx.x == 0 ? bndu : bndd;
    int g = threadIdx.x;
    if (g > NG) return;
    int lo = 0, hi = n;
    while (lo < hi) { int m = (lo + hi) >> 1; if (b[m] < g) lo = m + 1; else hi = m; }
    o[g] = lo;
}

// ---------------- CSR mean aggregation: bf16 gather -> bf16 mean rows ----------------
__global__ __launch_bounds__(256) void agg_kernel(
    const ushort* __restrict__ xb,
    const int* __restrict__ rp, const int* __restrict__ csr, int M,
    ushort* __restrict__ mean)
{
    int wave = threadIdx.x >> 6, lane = threadIdx.x & 63;
    int row = blockIdx.x * 4 + wave;
    if (row >= M) return;
    int s0 = rp[row], s1 = rp[row + 1];
    float ax = 0.f, ay = 0.f;
    int j = s0;
    for (; j + 8 <= s1; j += 8) {
        unsigned int v0 = *(const unsigned int*)&xb[(size_t)csr[j + 0] * 128 + lane * 2];
        unsigned int v1 = *(const unsigned int*)&xb[(size_t)csr[j + 1] * 128 + lane * 2];
        unsigned int v2 = *(const unsigned int*)&xb[(size_t)csr[j + 2] * 128 + lane * 2];
        unsigned int v3 = *(const unsigned int*)&xb[(size_t)csr[j + 3] * 128 + lane * 2];
        unsigned int v4 = *(const unsigned int*)&xb[(size_t)csr[j + 4] * 128 + lane * 2];
        unsigned int v5 = *(const unsigned int*)&xb[(size_t)csr[j + 5] * 128 + lane * 2];
        unsigned int v6 = *(const unsigned int*)&xb[(size_t)csr[j + 6] * 128 + lane * 2];
        unsigned int v7 = *(const unsigned int*)&xb[(size_t)csr[j + 7] * 128 + lane * 2];
        ax += __uint_as_float(v0 << 16) + __uint_as_float(v1 << 16)
            + __uint_as_float(v2 << 16) + __uint_as_float(v3 << 16)
            + __uint_as_float(v4 << 16) + __uint_as_float(v5 << 16)
            + __uint_as_float(v6 << 16) + __uint_as_float(v7 << 16);
        ay += __uint_as_float(v0 & 0xffff0000u) + __uint_as_float(v1 & 0xffff0000u)
            + __uint_as_float(v2 & 0xffff0000u) + __uint_as_float(v3 & 0xffff0000u)
            + __uint_as_float(v4 & 0xffff0000u) + __uint_as_float(v5 & 0xffff0000u)
            + __uint_as_float(v6 & 0xffff0000u) + __uint_as_float(v7 & 0xffff0000u);
    }
    for (; j < s1; ++j) {
        unsigned int v = *(const unsigned int*)&xb[(size_t)csr[j] * 128 + lane * 2];
        ax += __uint_as_float(v << 16);
        ay += __uint_as_float(v & 0xffff0000u);
    }
    int deg = s1 - s0;
    float sc = 1.f / (float)(deg > 1 ? deg : 1);
    unsigned int pk = (unsigned int)f2bf(ax * sc) | ((unsigned int)f2bf(ay * sc) << 16);
    *(unsigned int*)&mean[(size_t)row * 128 + lane * 2] = pk;
}

// ---------------- MFMA multi-term GEMM: C = relu(sum A_t @ W_t + bias) -> bf16 ----------------
template<int NA>
__global__ __launch_bounds__(256) void gemm_mfma(
    const ushort* __restrict__ A0, const ushort* __restrict__ A1, const ushort* __restrict__ A2,
    const ushort* __restrict__ Wt0, const ushort* __restrict__ Wt1, const ushort* __restrict__ Wt2,
    int M, const float* __restrict__ bias, ushort* __restrict__ C)
{
    int wave = threadIdx.x >> 6, lane = threadIdx.x & 63;
    int row0 = blockIdx.x * 64 + wave * 16;
    int r  = lane & 15;
    int kg = lane >> 4;
    f32x4 acc[8];
    #pragma unroll
    for (int nt = 0; nt < 8; ++nt) acc[nt] = (f32x4){0.f, 0.f, 0.f, 0.f};

    int arow = row0 + r;
    int arow_c = arow < M ? arow : 0;
    #pragma unroll
    for (int term = 0; term < NA; ++term) {
        const ushort* A  = (term == 0) ? A0  : (term == 1 ? A1  : A2);
        const ushort* Wt = (term == 0) ? Wt0 : (term == 1 ? Wt1 : Wt2);
        #pragma unroll
        for (int kk = 0; kk < 4; ++kk) {
            bf16x8 a = *(const bf16x8*)&A[(size_t)arow_c * 128 + kk * 32 + kg * 8];
            #pragma unroll
            for (int nt = 0; nt < 8; ++nt) {
                bf16x8 b = *(const bf16x8*)&Wt[(size_t)(nt * 16 + r) * 128 + kk * 32 + kg * 8];
                acc[nt] = __builtin_amdgcn_mfma_f32_16x16x32_bf16(a, b, acc[nt], 0, 0, 0);
            }
        }
    }

    #pragma unroll
    for (int nt = 0; nt < 8; ++nt) {
        int col = nt * 16 + r;
        float bv = bias[col];
        #pragma unroll
        for (int j = 0; j < 4; ++j) {
            int orow = row0 + kg * 4 + j;
            if (orow < M) {
                float v = fmaxf(acc[nt][j] + bv, 0.f);
                C[(size_t)orow * 128 + col] = f2bf(v);
            }
        }
    }
}

// ---------------- fused layer-2 agg + per-graph pool (8 rows/wave, replicated pool) ----------------
__global__ __launch_bounds__(256) void aggpool_kernel(
    const ushort* __restrict__ xb,
    const int* __restrict__ rp, const int* __restrict__ csr,
    const int* __restrict__ batch, int M,
    float* __restrict__ pool /* [REP][64][128], pre-zeroed */)
{
    int wave = threadIdx.x >> 6, lane = threadIdx.x & 63;
    int r0 = (blockIdx.x * 4 + wave) * 8;
    if (r0 >= M) return;
    int r1 = min(M, r0 + 8);
    float* p = pool + (size_t)(blockIdx.x & (REP - 1)) * NG * 128;
    float ax = 0.f, ay = 0.f;
    int curg = batch[r0];
    for (int row = r0; row < r1; ++row) {
        int g = batch[row];
        if (g != curg) {
            atomicAdd(&p[curg * 128 + lane * 2],     ax);
            atomicAdd(&p[curg * 128 + lane * 2 + 1], ay);
            ax = 0.f; ay = 0.f; curg = g;
        }
        int s0 = rp[row], s1 = rp[row + 1];
        float sx = 0.f, sy = 0.f;
        int j = s0;
        for (; j + 8 <= s1; j += 8) {
            unsigned int v0 = *(const unsigned int*)&xb[(size_t)csr[j + 0] * 128 + lane * 2];
            unsigned int v1 = *(const unsigned int*)&xb[(size_t)csr[j + 1] * 128 + lane * 2];
            unsigned int v2 = *(const unsigned int*)&xb[(size_t)csr[j + 2] * 128 + lane * 2];
            unsigned int v3 = *(const unsigned int*)&xb[(size_t)csr[j + 3] * 128 + lane * 2];
            unsigned int v4 = *(const unsigned int*)&xb[(size_t)csr[j + 4] * 128 + lane * 2];
            unsigned int v5 = *(const unsigned int*)&xb[(size_t)csr[j + 5] * 128 + lane * 2];
            unsigned int v6 = *(const unsigned int*)&xb[(size_t)csr[j + 6] * 128 + lane * 2];
            unsigned int v7 = *(const unsigned int*)&xb[(size_t)csr[j + 7] * 128 + lane * 2];
            sx += __uint_as_float(v0 << 16) + __uint_as_float(v1 << 16)
                + __uint_as_float(v2 << 16) + __uint_as_float(v3 << 16)
                + __uint_as_float(v4 << 16) + __uint_as_float(v5 << 16)
                + __uint_as_float(v6 << 16) + __uint_as_float(v7 << 16);
            sy += __uint_as_float(v0 & 0xffff0000u) + __uint_as_float(v1 & 0xffff0000u)
                + __uint_as_float(v2 & 0xffff0000u) + __uint_as_float(v3 & 0xffff0000u)
                + __uint_as_float(v4 & 0xffff0000u) + __uint_as_float(v5 & 0xffff0000u)
                + __uint_as_float(v6 & 0xffff0000u) + __uint_as_float(v7 & 0xffff0000u);
        }
        for (; j < s1; ++j) {
            unsigned int v = *(const unsigned int*)&xb[(size_t)csr[j] * 128 + lane * 2];
            sx += __uint_as_float(v << 16);
            sy += __uint_as_float(v & 0xffff0000u);
        }
        int deg = s1 - s0;
        float sc = 1.f / (float)(deg > 1 ? deg : 1);
        ax += sx * sc; ay += sy * sc;
    }
    atomicAdd(&p[curg * 128 + lane * 2],     ax);
    atomicAdd(&p[curg * 128 + lane * 2 + 1], ay);
}

// ---------------- per-graph row-sum pool over bf16 x (batch sorted) ----------------
__global__ __launch_bounds__(256) void rowpool_kernel(const ushort* __restrict__ xb,
                                                      const int* __restrict__ bnd,
                                                      float* __restrict__ pool)
{
    int g = blockIdx.x;
    int lo = bnd[g], hi = bnd[g + 1];
    int c2 = threadIdx.x & 63, half = threadIdx.x >> 6;
    float sx = 0.f, sy = 0.f;
    for (int r = lo + half; r < hi; r += 4) {
        unsigned int v = *(const unsigned int*)&xb[(size_t)r * 128 + c2 * 2];
        sx += __uint_as_float(v << 16);
        sy += __uint_as_float(v & 0xffff0000u);
    }
    __shared__ float ls[256 * 2];
    ls[threadIdx.x * 2]     = sx;
    ls[threadIdx.x * 2 + 1] = sy;
    __syncthreads();
    if (half == 0) {
        float ox = ls[c2 * 2] + ls[(64 + c2) * 2] + ls[(128 + c2) * 2] + ls[(192 + c2) * 2];
        float oy = ls[c2 * 2 + 1] + ls[(64 + c2) * 2 + 1] + ls[(128 + c2) * 2 + 1] + ls[(192 + c2) * 2 + 1];
        pool[g * 128 + c2 * 2]     = ox;
        pool[g * 128 + c2 * 2 + 1] = oy;
    }
}

// ---------------- final: layer-2 matmuls at graph level + MLP + log_softmax ----------------
__global__ __launch_bounds__(128) void final_kernel(
    const float* __restrict__ pmdu, const float* __restrict__ pmuu, const float* __restrict__ pmud,
    const float* __restrict__ pu1,  const float* __restrict__ pd1,
    const int* __restrict__ bndu, const int* __restrict__ bndd,
    const float* __restrict__ Wl2_du, const float* __restrict__ bl2_du, const float* __restrict__ Wr2_du,
    const float* __restrict__ Wl2_uu, const float* __restrict__ bl2_uu, const float* __restrict__ Wr2_uu,
    const float* __restrict__ Wl2_ud, const float* __restrict__ bl2_ud, const float* __restrict__ Wr2_ud,
    const float* __restrict__ W1, const float* __restrict__ b1,
    const float* __restrict__ W2, const float* __restrict__ b2,
    float* __restrict__ out)
{
    int g = blockIdx.x, t = threadIdx.x;
    __shared__ float smdu[128], smuu[128], smud[128], su1[128], sd1[128];
    __shared__ float xrow[256], h[128], lg[2];
    float vdu = 0.f, vuu = 0.f, vud = 0.f;
    #pragma unroll
    for (int r = 0; r < REP; ++r) {
        vdu += pmdu[(size_t)r * NG * 128 + g * 128 + t];
        vuu += pmuu[(size_t)r * NG * 128 + g * 128 + t];
        vud += pmud[(size_t)r * NG * 128 + g * 128 + t];
    }
    smdu[t] = vdu;
    smuu[t] = vuu;
    smud[t] = vud;
    su1[t]  = pu1[g * 128 + t];
    sd1[t]  = pd1[g * 128 + t];
    __syncthreads();
    float ncu = (float)(bndu[g + 1] - bndu[g]);
    float ncd = (float)(bndd[g + 1] - bndd[g]);
    float cu = ncu > 1.f ? ncu : 1.f, cd = ncd > 1.f ? ncd : 1.f;
    float accu = ncu * (bl2_du[t] + bl2_uu[t]);
    float accd = ncd * bl2_ud[t];
    for (int k = 0; k < 128; ++k) {
        accu += smdu[k] * Wl2_du[k * 128 + t]
              + smuu[k] * Wl2_uu[k * 128 + t]
              + su1[k]  * (Wr2_du[k * 128 + t] + Wr2_uu[k * 128 + t]);
        accd += smud[k] * Wl2_ud[k * 128 + t]
              + sd1[k]  * Wr2_ud[k * 128 + t];
    }
    xrow[t]       = accu / cu;
    xrow[128 + t] = accd / cd;
    __syncthreads();
    float hh = b1[t];
    for (int k = 0; k < 256; ++k) hh += xrow[k] * W1[k * 128 + t];
    h[t] = fmaxf(hh, 0.f);
    __syncthreads();
    if (t < 2) {
        float l = b2[t];
        for (int k = 0; k < 128; ++k) l += h[k] * W2[k * 2 + t];
        lg[t] = l;
    }
    __syncthreads();
    if (t == 0) {
        float m = fmaxf(lg[0], lg[1]);
        float lse = m + logf(expf(lg[0] - m) + expf(lg[1] - m));
        out[g * 2 + 0] = lg[0] - lse;
        out[g * 2 + 1] = lg[1] - lse;
    }
}

extern "C" void kernel_launch(void* const* d_in, const int* in_sizes, int n_in,
                              void* d_out, int out_size, void* d_ws, size_t ws_size,
                              hipStream_t stream)
{
    const float* x_user = (const float*)d_in[0];
    const float* x_drug = (const float*)d_in[1];
    const int* ei_ud = (const int*)d_in[2];
    const int* ei_du = (const int*)d_in[3];
    const int* ei_uu = (const int*)d_in[4];
    const int* batch_u = (const int*)d_in[5];
    const int* batch_d = (const int*)d_in[6];
    const float* Wl1_ud = (const float*)d_in[7];  const float* bl1_ud = (const float*)d_in[8];  const float* Wr1_ud = (const float*)d_in[9];
    const float* Wl1_du = (const float*)d_in[10]; const float* bl1_du = (const float*)d_in[11]; const float* Wr1_du = (const float*)d_in[12];
    const float* Wl1_uu = (const float*)d_in[13]; const float* bl1_uu = (const float*)d_in[14]; const float* Wr1_uu = (const float*)d_in[15];
    const float* Wl2_ud = (const float*)d_in[16]; const float* bl2_ud = (const float*)d_in[17]; const float* Wr2_ud = (const float*)d_in[18];
    const float* Wl2_du = (const float*)d_in[19]; const float* bl2_du = (const float*)d_in[20]; const float* Wr2_du = (const float*)d_in[21];
    const float* Wl2_uu = (const float*)d_in[22]; const float* bl2_uu = (const float*)d_in[23]; const float* Wr2_uu = (const float*)d_in[24];
    const float* W1 = (const float*)d_in[25]; const float* b1 = (const float*)d_in[26];
    const float* W2 = (const float*)d_in[27]; const float* b2 = (const float*)d_in[28];
    (void)n_in; (void)out_size; (void)ws_size;

    const int Nu = in_sizes[0] / 128;
    const int Nd = in_sizes[1] / 128;
    const int E_ud = in_sizes[2] / 2;
    const int E_du = in_sizes[3] / 2;
    const int E_uu = in_sizes[4] / 2;
    const int nbk_u = (Nu + 63) >> 6;
    const int nbk_d = (Nd + 63) >> 6;

    char* ws = (char*)d_ws;
    size_t off = 0;
    auto alloc = [&](size_t bytes) -> void* {
        void* p = ws + off;
        off = (off + bytes + 255) & ~(size_t)255;
        return p;
    };
    int2* ebuf_ud = (int2*)alloc((size_t)E_ud * 8);
    int2* ebuf_du = (int2*)alloc((size_t)E_du * 8);
    int2* ebuf_uu = (int2*)alloc((size_t)E_uu * 8);
    int* cntA   = (int*)alloc((size_t)NBK_MAX * GSC * 4);   // reused per type
    int* basesA = (int*)alloc((size_t)NBK_MAX * GSC * 4);   // reused per type
    int* btot   = (int*)alloc((size_t)NBK_MAX * 4);
    int* bbase_ud = (int*)alloc((size_t)(NBK_MAX + 1) * 4);
    int* bbase_du = (int*)alloc((size_t)(NBK_MAX + 1) * 4);
    int* bbase_uu = (int*)alloc((size_t)(NBK_MAX + 1) * 4);
    int* csr_ud = (int*)alloc((size_t)E_ud * 4);
    int* csr_du = (int*)alloc((size_t)E_du * 4);
    int* csr_uu = (int*)alloc((size_t)E_uu * 4);
    int* rp_ud = (int*)alloc((size_t)(Nd + 1) * 4);
    int* rp_du = (int*)alloc((size_t)(Nu + 1) * 4);
    int* rp_uu = (int*)alloc((size_t)(Nu + 1) * 4);
    ushort* xb_u = (ushort*)alloc((size_t)Nu * 128 * 2);
    ushort* xb_d = (ushort*)alloc((size_t)Nd * 128 * 2);
    // layer-1 mean buffers overlay the ebufs (dead after csrify)
    ushort* mean_du = (ushort*)ebuf_du;   // [Nu,128] bf16 = 12.8MB over E_du*8 = 12.8MB
    ushort* mean_uu = (ushort*)ebuf_uu;   // [Nu,128]
    ushort* mean_ud = (ushort*)ebuf_ud;   // [Nd,128]
    ushort* u1b = (ushort*)alloc((size_t)Nu * 128 * 2);
    ushort* d1b = (ushort*)alloc((size_t)Nd * 128 * 2);
    float* pmdu = (float*)alloc((size_t)REP * NG * 128 * 4);
    float* pmuu = (float*)alloc((size_t)REP * NG * 128 * 4);
    float* pmud = (float*)alloc((size_t)REP * NG * 128 * 4);
    char* zero2_end = ws + off;
    float* pu1  = (float*)alloc(NG * 128 * 4);
    float* pd1  = (float*)alloc(NG * 128 * 4);
    int* bnd_u = (int*)alloc((NG + 1) * 4);
    int* bnd_d = (int*)alloc((NG + 1) * 4);
    ushort* Wt_ru  = (ushort*)alloc(128 * 128 * 2);
    ushort* Wt_ldu = (ushort*)alloc(128 * 128 * 2);
    ushort* Wt_luu = (ushort*)alloc(128 * 128 * 2);
    ushort* Wt_rud = (ushort*)alloc(128 * 128 * 2);
    ushort* Wt_lud = (ushort*)alloc(128 * 128 * 2);
    float* b1s_u  = (float*)alloc(128 * 4);

    const int* dst_ud = ei_ud + E_ud;
    const int* dst_du = ei_du + E_du;
    const int* dst_uu = ei_uu + E_uu;

    // ---- CSR build via LDS bucket sort (zero device atomics) ----
    bucket_count<<<GSC, 256, 0, stream>>>(dst_ud, E_ud, nbk_d, cntA);
    scan_blocks<<<nbk_d, GSC, 0, stream>>>(cntA, nbk_d, basesA, btot);
    scan_buckets<<<1, 1024, 0, stream>>>(btot, nbk_d, bbase_ud);
    bucket_scatter<<<GSC, 256, 0, stream>>>(ei_ud, dst_ud, E_ud, nbk_d, basesA, bbase_ud, ebuf_ud);
    csrify_kernel<<<nbk_d, 256, 0, stream>>>(ebuf_ud, bbase_ud, Nd, E_ud, rp_ud, csr_ud);

    bucket_count<<<GSC, 256, 0, stream>>>(dst_du, E_du, nbk_u, cntA);
    scan_blocks<<<nbk_u, GSC, 0, stream>>>(cntA, nbk_u, basesA, btot);
    scan_buckets<<<1, 1024, 0, stream>>>(btot, nbk_u, bbase_du);
    bucket_scatter<<<GSC, 256, 0, stream>>>(ei_du, dst_du, E_du, nbk_u, basesA, bbase_du, ebuf_du);
    csrify_kernel<<<nbk_u, 256, 0, stream>>>(ebuf_du, bbase_du, Nu, E_du, rp_du, csr_du);

    bucket_count<<<GSC, 256, 0, stream>>>(dst_uu, E_uu, nbk_u, cntA);
    scan_blocks<<<nbk_u, GSC, 0, stream>>>(cntA, nbk_u, basesA, btot);
    scan_buckets<<<1, 1024, 0, stream>>>(btot, nbk_u, bbase_uu);
    bucket_scatter<<<GSC, 256, 0, stream>>>(ei_uu, dst_uu, E_uu, nbk_u, basesA, bbase_uu, ebuf_uu);
    csrify_kernel<<<nbk_u, 256, 0, stream>>>(ebuf_uu, bbase_uu, Nu, E_uu, rp_uu, csr_uu);

    // ---- graph boundaries, bf16 inputs, weight prep ----
    bounds_kernel<<<2, NG + 1, 0, stream>>>(batch_u, Nu, batch_d, Nd, bnd_u, bnd_d);
    cvt_kernel<<<(Nu * 32 + 255) / 256, 256, 0, stream>>>(x_user, xb_u, Nu * 32);
    cvt_kernel<<<(Nd * 32 + 255) / 256, 256, 0, stream>>>(x_drug, xb_d, Nd * 32);
    wprep_kernel<<<5, 256, 0, stream>>>(Wr1_du, Wr1_uu, Wt_ru,
                                        Wl1_du, Wt_ldu, Wl1_uu, Wt_luu,
                                        Wr1_ud, Wt_rud, Wl1_ud, Wt_lud);
    add2_kernel<<<1, 128, 0, stream>>>(bl1_du, bl1_uu, b1s_u, 128);

    // ---- layer-1 aggregation (register-gather; means overlay dead ebufs) ----
    agg_kernel<<<(Nu + 3) / 4, 256, 0, stream>>>(xb_d, rp_du, csr_du, Nu, mean_du);
    agg_kernel<<<(Nu + 3) / 4, 256, 0, stream>>>(xb_u, rp_uu, csr_uu, Nu, mean_uu);
    agg_kernel<<<(Nd + 3) / 4, 256, 0, stream>>>(xb_u, rp_ud, csr_ud, Nd, mean_ud);

    // ---- layer-1 MFMA GEMMs -> bf16 ----
    gemm_mfma<3><<<(Nu + 63) / 64, 256, 0, stream>>>(xb_u, mean_du, mean_uu,
                                                     Wt_ru, Wt_ldu, Wt_luu, Nu, b1s_u, u1b);
    gemm_mfma<2><<<(Nd + 63) / 64, 256, 0, stream>>>(xb_d, mean_ud, nullptr,
                                                     Wt_rud, Wt_lud, nullptr, Nd, bl1_ud, d1b);

    // ---- layer 2: fused CSR-mean + per-graph pool (replicated pools) ----
    hipMemsetAsync(pmdu, 0, (size_t)(zero2_end - (char*)pmdu), stream);
    aggpool_kernel<<<(Nu + 31) / 32, 256, 0, stream>>>(d1b, rp_du, csr_du, batch_u, Nu, pmdu);
    aggpool_kernel<<<(Nu + 31) / 32, 256, 0, stream>>>(u1b, rp_uu, csr_uu, batch_u, Nu, pmuu);
    aggpool_kernel<<<(Nd + 31) / 32, 256, 0, stream>>>(u1b, rp_ud, csr_ud, batch_d, Nd, pmud);

    // ---- root-term pools (direct store) ----
    rowpool_kernel<<<NG, 256, 0, stream>>>(u1b, bnd_u, pu1);
    rowpool_kernel<<<NG, 256, 0, stream>>>(d1b, bnd_d, pd1);

    // ---- graph-level layer-2 matmuls + MLP + log_softmax ----
    final_kernel<<<NG, 128, 0, stream>>>(pmdu, pmuu, pmud, pu1, pd1, bnd_u, bnd_d,
                                         Wl2_du, bl2_du, Wr2_du,
                                         Wl2_uu, bl2_uu, Wr2_uu,
                                         Wl2_ud, bl2_ud, Wr2_ud,
                                         W1, b1, W2, b2, (float*)d_out);
}

// Round 11
// 626.430 us; speedup vs baseline: 13.4903x; 1.1834x over previous
//
#include <hip/hip_runtime.h>

#define NG 64
#define REP 8          // aggpool replicas
#define GSC 512        // scatter grid blocks
#define NBK_MAX 1024   // max buckets (N <= 65536)

typedef __bf16 bf16x8 __attribute__((ext_vector_type(8)));
typedef float  f32x4  __attribute__((ext_vector_type(4)));

__device__ __forceinline__ ushort f2bf(float f) {
    unsigned int b = __float_as_uint(f);
    b += 0x7fffu + ((b >> 16) & 1u);   // RTNE
    return (ushort)(b >> 16);
}

// ---------------- pass A: per-block bucket counts (LDS int hist), 3 types ----------------
__global__ __launch_bounds__(256) void bucket_count3(
    const int* __restrict__ d0, int E0, int nbk0, int* __restrict__ c0,
    const int* __restrict__ d1, int E1, int nbk1, int* __restrict__ c1,
    const int* __restrict__ d2, int E2, int nbk2, int* __restrict__ c2)
{
    const int* dst; int E, nbk; int* cntA;
    if (blockIdx.y == 0) { dst = d0; E = E0; nbk = nbk0; cntA = c0; }
    else if (blockIdx.y == 1) { dst = d1; E = E1; nbk = nbk1; cntA = c1; }
    else { dst = d2; E = E2; nbk = nbk2; cntA = c2; }
    __shared__ int h[NBK_MAX];
    for (int i = threadIdx.x; i < nbk; i += 256) h[i] = 0;
    __syncthreads();
    int chunk = (E + GSC - 1) / GSC;
    int i0 = blockIdx.x * chunk, i1 = min(E, i0 + chunk);
    for (int i = i0 + threadIdx.x; i < i1; i += 256)
        atomicAdd(&h[dst[i] >> 6], 1);
    __syncthreads();
    for (int i = threadIdx.x; i < nbk; i += 256)
        cntA[(size_t)i * GSC + blockIdx.x] = h[i];
}

// ---------------- in-place scan over blocks per bucket, 3 types ----------------
__global__ __launch_bounds__(GSC) void scan_blocks3(
    int* __restrict__ c0, int nbk0, int* __restrict__ bt0,
    int* __restrict__ c1, int nbk1, int* __restrict__ bt1,
    int* __restrict__ c2, int nbk2, int* __restrict__ bt2)
{
    int* cntA; int nbk; int* btot;
    if (blockIdx.y == 0) { cntA = c0; nbk = nbk0; btot = bt0; }
    else if (blockIdx.y == 1) { cntA = c1; nbk = nbk1; btot = bt1; }
    else { cntA = c2; nbk = nbk2; btot = bt2; }
    int b = blockIdx.x;
    if (b >= nbk) return;
    int t = threadIdx.x, lane = t & 63, wv = t >> 6;   // 8 waves
    __shared__ int wsum[8];
    int v = cntA[(size_t)b * GSC + t];
    int x = v;
    #pragma unroll
    for (int off = 1; off < 64; off <<= 1) { int u = __shfl_up(x, off, 64); if (lane >= off) x += u; }
    if (lane == 63) wsum[wv] = x;
    __syncthreads();
    if (wv == 0 && lane < 8) {
        int w = wsum[lane];
        #pragma unroll
        for (int off = 1; off < 8; off <<= 1) { int u = __shfl_up(w, off, 64); if (lane >= off) w += u; }
        wsum[lane] = w;
    }
    __syncthreads();
    int incl = x + (wv > 0 ? wsum[wv - 1] : 0);
    cntA[(size_t)b * GSC + t] = incl - v;       // in-place exclusive base
    if (t == GSC - 1) btot[b] = incl;
}

// ---------------- exclusive scan of bucket totals -> bbase, 3 types ----------------
__global__ __launch_bounds__(1024) void scan_buckets3(
    const int* __restrict__ bt0, int nbk0, int* __restrict__ bb0,
    const int* __restrict__ bt1, int nbk1, int* __restrict__ bb1,
    const int* __restrict__ bt2, int nbk2, int* __restrict__ bb2)
{
    const int* btot; int nbk; int* bbase;
    if (blockIdx.x == 0) { btot = bt0; nbk = nbk0; bbase = bb0; }
    else if (blockIdx.x == 1) { btot = bt1; nbk = nbk1; bbase = bb1; }
    else { btot = bt2; nbk = nbk2; bbase = bb2; }
    int t = threadIdx.x, lane = t & 63, wv = t >> 6;
    __shared__ int wsum[16];
    int v = (t < nbk) ? btot[t] : 0;
    int x = v;
    #pragma unroll
    for (int off = 1; off < 64; off <<= 1) { int u = __shfl_up(x, off, 64); if (lane >= off) x += u; }
    if (lane == 63) wsum[wv] = x;
    __syncthreads();
    if (wv == 0 && lane < 16) {
        int w = wsum[lane];
        #pragma unroll
        for (int off = 1; off < 16; off <<= 1) { int u = __shfl_up(w, off, 64); if (lane >= off) w += u; }
        wsum[lane] = w;
    }
    __syncthreads();
    int incl = x + (wv > 0 ? wsum[wv - 1] : 0);
    if (t <= nbk) bbase[t] = incl - v;
}

// ---------------- pass B: scatter (src,dst) into bucket-grouped ebuf, 3 types ----------------
__global__ __launch_bounds__(256) void bucket_scatter3(
    const int* __restrict__ s0, const int* __restrict__ d0, int E0, int nbk0,
    const int* __restrict__ ba0, const int* __restrict__ bb0, int2* __restrict__ eb0,
    const int* __restrict__ s1, const int* __restrict__ d1, int E1, int nbk1,
    const int* __restrict__ ba1, const int* __restrict__ bb1, int2* __restrict__ eb1,
    const int* __restrict__ s2, const int* __restrict__ d2, int E2, int nbk2,
    const int* __restrict__ ba2, const int* __restrict__ bb2, int2* __restrict__ eb2)
{
    const int *src, *dst, *basesA, *bbase; int E, nbk; int2* ebuf;
    if (blockIdx.y == 0) { src = s0; dst = d0; E = E0; nbk = nbk0; basesA = ba0; bbase = bb0; ebuf = eb0; }
    else if (blockIdx.y == 1) { src = s1; dst = d1; E = E1; nbk = nbk1; basesA = ba1; bbase = bb1; ebuf = eb1; }
    else { src = s2; dst = d2; E = E2; nbk = nbk2; basesA = ba2; bbase = bb2; ebuf = eb2; }
    __shared__ int cur[NBK_MAX];
    for (int i = threadIdx.x; i < nbk; i += 256)
        cur[i] = bbase[i] + basesA[(size_t)i * GSC + blockIdx.x];
    __syncthreads();
    int chunk = (E + GSC - 1) / GSC;
    int i0 = blockIdx.x * chunk, i1 = min(E, i0 + chunk);
    for (int i = i0 + threadIdx.x; i < i1; i += 256) {
        int d = dst[i];
        int pos = atomicAdd(&cur[d >> 6], 1);
        ebuf[pos] = make_int2(src[i], d);
    }
}

// ---------------- per-bucket exact CSR from bucket-grouped edges, 3 types ----------------
__global__ __launch_bounds__(256) void csrify3(
    const int2* __restrict__ eb0, const int* __restrict__ bb0, int M0, int E0, int nbk0,
    int* __restrict__ rp0, int* __restrict__ cs0,
    const int2* __restrict__ eb1, const int* __restrict__ bb1, int M1, int E1, int nbk1,
    int* __restrict__ rp1, int* __restrict__ cs1,
    const int2* __restrict__ eb2, const int* __restrict__ bb2, int M2, int E2, int nbk2,
    int* __restrict__ rp2, int* __restrict__ cs2)
{
    const int2* ebuf; const int* bbase; int M, E, nbk; int *rp, *csr;
    if (blockIdx.y == 0) { ebuf = eb0; bbase = bb0; M = M0; E = E0; nbk = nbk0; rp = rp0; csr = cs0; }
    else if (blockIdx.y == 1) { ebuf = eb1; bbase = bb1; M = M1; E = E1; nbk = nbk1; rp = rp1; csr = cs1; }
    else { ebuf = eb2; bbase = bb2; M = M2; E = E2; nbk = nbk2; rp = rp2; csr = cs2; }
    if ((int)blockIdx.x >= nbk) return;
    __shared__ int hist[64], cur[64];
    int t = threadIdx.x;
    if (t < 64) hist[t] = 0;
    __syncthreads();
    int e0 = bbase[blockIdx.x], e1 = bbase[blockIdx.x + 1];
    for (int e = e0 + t; e < e1; e += 256)
        atomicAdd(&hist[ebuf[e].y & 63], 1);
    __syncthreads();
    if (t < 64) {
        int x = hist[t];
        #pragma unroll
        for (int off = 1; off < 64; off <<= 1) { int u = __shfl_up(x, off, 64); if (t >= off) x += u; }
        int ex = x - hist[t];
        cur[t] = ex;
        int row = (blockIdx.x << 6) + t;
        if (row < M) rp[row] = e0 + ex;
    }
    if (blockIdx.x == 0 && t == 0) rp[M] = E;
    __syncthreads();
    for (int e = e0 + t; e < e1; e += 256) {
        int2 p = ebuf[e];
        int pos = atomicAdd(&cur[p.y & 63], 1);
        csr[e0 + pos] = p.x;
    }
}

// ---------------- elementwise add (bias sums) ----------------
__global__ void add2_kernel(const float* __restrict__ a, const float* __restrict__ b,
                            float* __restrict__ o, int n) {
    int i = blockIdx.x * blockDim.x + threadIdx.x;
    if (i < n) o[i] = a[i] + b[i];
}

// ---------------- f32 -> bf16 conversion ----------------
__global__ void cvt_kernel(const float* __restrict__ x, ushort* __restrict__ o, int n4) {
    int i = blockIdx.x * blockDim.x + threadIdx.x;
    if (i >= n4) return;
    float4 v = ((const float4*)x)[i];
    ushort4 r;
    r.x = f2bf(v.x); r.y = f2bf(v.y); r.z = f2bf(v.z); r.w = f2bf(v.w);
    ((ushort4*)o)[i] = r;
}

// ---------------- weight prep: Wt[n][k] = bf16(Wa[k][n] (+Wb[k][n])) ----------------
__global__ void wprep_kernel(
    const float* __restrict__ Wa0, const float* __restrict__ Wb0, ushort* __restrict__ Wt0,
    const float* __restrict__ Wa1, ushort* __restrict__ Wt1,
    const float* __restrict__ Wa2, ushort* __restrict__ Wt2,
    const float* __restrict__ Wa3, ushort* __restrict__ Wt3,
    const float* __restrict__ Wa4, ushort* __restrict__ Wt4)
{
    const float* Wa; const float* Wb = nullptr; ushort* Wt;
    switch (blockIdx.x) {
        case 0: Wa = Wa0; Wb = Wb0; Wt = Wt0; break;
        case 1: Wa = Wa1; Wt = Wt1; break;
        case 2: Wa = Wa2; Wt = Wt2; break;
        case 3: Wa = Wa3; Wt = Wt3; break;
        default: Wa = Wa4; Wt = Wt4; break;
    }
    for (int idx = threadIdx.x; idx < 128 * 128; idx += 256) {
        int n = idx >> 7, k = idx & 127;
        float v = Wa[k * 128 + n];
        if (Wb) v += Wb[k * 128 + n];
        Wt[idx] = f2bf(v);
    }
}

// ---------------- graph boundaries via binary search (batch is sorted) ----------------
__global__ void bounds_kernel(const int* __restrict__ bu, int nu,
                              const int* __restrict__ bd, int nd,
                              int* __restrict__ bndu, int* __restrict__ bndd)
{
    const int* b = blockIdx.x == 0 ? bu : bd;
    int        n = blockIdx.x == 0 ? nu : nd;
    int*       o = blockIdx.x == 0 ? bndu : bndd;
    int g = threadIdx.x;
    if (g > NG) return;
    int lo = 0, hi = n;
    while (lo < hi) { int m = (lo + hi) >> 1; if (b[m] < g) lo = m + 1; else hi = m; }
    o[g] = lo;
}

// ---------------- CSR mean aggregation (3 types in one launch) ----------------
__global__ __launch_bounds__(256) void agg3_kernel(
    const ushort* __restrict__ x0, const int* __restrict__ rpa, const int* __restrict__ csa, int Ma, ushort* __restrict__ ma,
    const ushort* __restrict__ x1, const int* __restrict__ rpb, const int* __restrict__ csb, int Mb, ushort* __restrict__ mb,
    const ushort* __restrict__ x2, const int* __restrict__ rpc, const int* __restrict__ csc, int Mc, ushort* __restrict__ mc)
{
    const ushort* xb; const int *rp, *csr; int M; ushort* mean;
    if (blockIdx.y == 0) { xb = x0; rp = rpa; csr = csa; M = Ma; mean = ma; }
    else if (blockIdx.y == 1) { xb = x1; rp = rpb; csr = csb; M = Mb; mean = mb; }
    else { xb = x2; rp = rpc; csr = csc; M = Mc; mean = mc; }
    int wave = threadIdx.x >> 6, lane = threadIdx.x & 63;
    int row = blockIdx.x * 4 + wave;
    if (row >= M) return;
    int s0 = rp[row], s1 = rp[row + 1];
    float ax = 0.f, ay = 0.f;
    int j = s0;
    for (; j + 8 <= s1; j += 8) {
        unsigned int v0 = *(const unsigned int*)&xb[(size_t)csr[j + 0] * 128 + lane * 2];
        unsigned int v1 = *(const unsigned int*)&xb[(size_t)csr[j + 1] * 128 + lane * 2];
        unsigned int v2 = *(const unsigned int*)&xb[(size_t)csr[j + 2] * 128 + lane * 2];
        unsigned int v3 = *(const unsigned int*)&xb[(size_t)csr[j + 3] * 128 + lane * 2];
        unsigned int v4 = *(const unsigned int*)&xb[(size_t)csr[j + 4] * 128 + lane * 2];
        unsigned int v5 = *(const unsigned int*)&xb[(size_t)csr[j + 5] * 128 + lane * 2];
        unsigned int v6 = *(const unsigned int*)&xb[(size_t)csr[j + 6] * 128 + lane * 2];
        unsigned int v7 = *(const unsigned int*)&xb[(size_t)csr[j + 7] * 128 + lane * 2];
        ax += __uint_as_float(v0 << 16) + __uint_as_float(v1 << 16)
            + __uint_as_float(v2 << 16) + __uint_as_float(v3 << 16)
            + __uint_as_float(v4 << 16) + __uint_as_float(v5 << 16)
            + __uint_as_float(v6 << 16) + __uint_as_float(v7 << 16);
        ay += __uint_as_float(v0 & 0xffff0000u) + __uint_as_float(v1 & 0xffff0000u)
            + __uint_as_float(v2 & 0xffff0000u) + __uint_as_float(v3 & 0xffff0000u)
            + __uint_as_float(v4 & 0xffff0000u) + __uint_as_float(v5 & 0xffff0000u)
            + __uint_as_float(v6 & 0xffff0000u) + __uint_as_float(v7 & 0xffff0000u);
    }
    for (; j < s1; ++j) {
        unsigned int v = *(const unsigned int*)&xb[(size_t)csr[j] * 128 + lane * 2];
        ax += __uint_as_float(v << 16);
        ay += __uint_as_float(v & 0xffff0000u);
    }
    int deg = s1 - s0;
    float sc = 1.f / (float)(deg > 1 ? deg : 1);
    unsigned int pk = (unsigned int)f2bf(ax * sc) | ((unsigned int)f2bf(ay * sc) << 16);
    *(unsigned int*)&mean[(size_t)row * 128 + lane * 2] = pk;
}

// ---------------- MFMA multi-term GEMM: C = relu(sum A_t @ W_t + bias) -> bf16 ----------------
template<int NA>
__global__ __launch_bounds__(256) void gemm_mfma(
    const ushort* __restrict__ A0, const ushort* __restrict__ A1, const ushort* __restrict__ A2,
    const ushort* __restrict__ Wt0, const ushort* __restrict__ Wt1, const ushort* __restrict__ Wt2,
    int M, const float* __restrict__ bias, ushort* __restrict__ C)
{
    int wave = threadIdx.x >> 6, lane = threadIdx.x & 63;
    int row0 = blockIdx.x * 64 + wave * 16;
    int r  = lane & 15;
    int kg = lane >> 4;
    f32x4 acc[8];
    #pragma unroll
    for (int nt = 0; nt < 8; ++nt) acc[nt] = (f32x4){0.f, 0.f, 0.f, 0.f};

    int arow = row0 + r;
    int arow_c = arow < M ? arow : 0;
    #pragma unroll
    for (int term = 0; term < NA; ++term) {
        const ushort* A  = (term == 0) ? A0  : (term == 1 ? A1  : A2);
        const ushort* Wt = (term == 0) ? Wt0 : (term == 1 ? Wt1 : Wt2);
        #pragma unroll
        for (int kk = 0; kk < 4; ++kk) {
            bf16x8 a = *(const bf16x8*)&A[(size_t)arow_c * 128 + kk * 32 + kg * 8];
            #pragma unroll
            for (int nt = 0; nt < 8; ++nt) {
                bf16x8 b = *(const bf16x8*)&Wt[(size_t)(nt * 16 + r) * 128 + kk * 32 + kg * 8];
                acc[nt] = __builtin_amdgcn_mfma_f32_16x16x32_bf16(a, b, acc[nt], 0, 0, 0);
            }
        }
    }

    #pragma unroll
    for (int nt = 0; nt < 8; ++nt) {
        int col = nt * 16 + r;
        float bv = bias[col];
        #pragma unroll
        for (int j = 0; j < 4; ++j) {
            int orow = row0 + kg * 4 + j;
            if (orow < M) {
                float v = fmaxf(acc[nt][j] + bv, 0.f);
                C[(size_t)orow * 128 + col] = f2bf(v);
            }
        }
    }
}

// ---------------- fused layer-2 agg + per-graph pool (4 rows/wave, replicated, 3 types) ----------------
__global__ __launch_bounds__(256) void aggpool3_kernel(
    const ushort* __restrict__ x0, const int* __restrict__ rpa, const int* __restrict__ csa,
    const int* __restrict__ ba, int Ma, float* __restrict__ pa,
    const ushort* __restrict__ x1, const int* __restrict__ rpb, const int* __restrict__ csb,
    const int* __restrict__ bb, int Mb, float* __restrict__ pb,
    const ushort* __restrict__ x2, const int* __restrict__ rpc, const int* __restrict__ csc,
    const int* __restrict__ bc, int Mc, float* __restrict__ pc)
{
    const ushort* xb; const int *rp, *csr, *batch; int M; float* pool;
    if (blockIdx.y == 0) { xb = x0; rp = rpa; csr = csa; batch = ba; M = Ma; pool = pa; }
    else if (blockIdx.y == 1) { xb = x1; rp = rpb; csr = csb; batch = bb; M = Mb; pool = pb; }
    else { xb = x2; rp = rpc; csr = csc; batch = bc; M = Mc; pool = pc; }
    int wave = threadIdx.x >> 6, lane = threadIdx.x & 63;
    int r0 = (blockIdx.x * 4 + wave) * 4;
    if (r0 >= M) return;
    int r1 = min(M, r0 + 4);
    float* p = pool + (size_t)(blockIdx.x & (REP - 1)) * NG * 128;
    float ax = 0.f, ay = 0.f;
    int curg = batch[r0];
    for (int row = r0; row < r1; ++row) {
        int g = batch[row];
        if (g != curg) {
            atomicAdd(&p[curg * 128 + lane * 2],     ax);
            atomicAdd(&p[curg * 128 + lane * 2 + 1], ay);
            ax = 0.f; ay = 0.f; curg = g;
        }
        int s0 = rp[row], s1 = rp[row + 1];
        float sx = 0.f, sy = 0.f;
        int j = s0;
        for (; j + 8 <= s1; j += 8) {
            unsigned int v0 = *(const unsigned int*)&xb[(size_t)csr[j + 0] * 128 + lane * 2];
            unsigned int v1 = *(const unsigned int*)&xb[(size_t)csr[j + 1] * 128 + lane * 2];
            unsigned int v2 = *(const unsigned int*)&xb[(size_t)csr[j + 2] * 128 + lane * 2];
            unsigned int v3 = *(const unsigned int*)&xb[(size_t)csr[j + 3] * 128 + lane * 2];
            unsigned int v4 = *(const unsigned int*)&xb[(size_t)csr[j + 4] * 128 + lane * 2];
            unsigned int v5 = *(const unsigned int*)&xb[(size_t)csr[j + 5] * 128 + lane * 2];
            unsigned int v6 = *(const unsigned int*)&xb[(size_t)csr[j + 6] * 128 + lane * 2];
            unsigned int v7 = *(const unsigned int*)&xb[(size_t)csr[j + 7] * 128 + lane * 2];
            sx += __uint_as_float(v0 << 16) + __uint_as_float(v1 << 16)
                + __uint_as_float(v2 << 16) + __uint_as_float(v3 << 16)
                + __uint_as_float(v4 << 16) + __uint_as_float(v5 << 16)
                + __uint_as_float(v6 << 16) + __uint_as_float(v7 << 16);
            sy += __uint_as_float(v0 & 0xffff0000u) + __uint_as_float(v1 & 0xffff0000u)
                + __uint_as_float(v2 & 0xffff0000u) + __uint_as_float(v3 & 0xffff0000u)
                + __uint_as_float(v4 & 0xffff0000u) + __uint_as_float(v5 & 0xffff0000u)
                + __uint_as_float(v6 & 0xffff0000u) + __uint_as_float(v7 & 0xffff0000u);
        }
        for (; j < s1; ++j) {
            unsigned int v = *(const unsigned int*)&xb[(size_t)csr[j] * 128 + lane * 2];
            sx += __uint_as_float(v << 16);
            sy += __uint_as_float(v & 0xffff0000u);
        }
        int deg = s1 - s0;
        float sc = 1.f / (float)(deg > 1 ? deg : 1);
        ax += sx * sc; ay += sy * sc;
    }
    atomicAdd(&p[curg * 128 + lane * 2],     ax);
    atomicAdd(&p[curg * 128 + lane * 2 + 1], ay);
}

// ---------------- 2-way per-graph row-sum pool (u1b, d1b) ----------------
__global__ __launch_bounds__(256) void pool2_kernel(
    const ushort* __restrict__ u1b, const ushort* __restrict__ d1b,
    const int* __restrict__ bndu, const int* __restrict__ bndd,
    float* __restrict__ pu1, float* __restrict__ pd1)
{
    const ushort* xb; const int* bnd; float* pool;
    if (blockIdx.y == 0) { xb = u1b; bnd = bndu; pool = pu1; }
    else { xb = d1b; bnd = bndd; pool = pd1; }
    int g = blockIdx.x;
    int lo = bnd[g], hi = bnd[g + 1];
    int c2 = threadIdx.x & 63, half = threadIdx.x >> 6;
    float sx = 0.f, sy = 0.f;
    for (int r = lo + half; r < hi; r += 4) {
        unsigned int v = *(const unsigned int*)&xb[(size_t)r * 128 + c2 * 2];
        sx += __uint_as_float(v << 16);
        sy += __uint_as_float(v & 0xffff0000u);
    }
    __shared__ float ls[256 * 2];
    ls[threadIdx.x * 2]     = sx;
    ls[threadIdx.x * 2 + 1] = sy;
    __syncthreads();
    if (half == 0) {
        float ox = ls[c2 * 2] + ls[(64 + c2) * 2] + ls[(128 + c2) * 2] + ls[(192 + c2) * 2];
        float oy = ls[c2 * 2 + 1] + ls[(64 + c2) * 2 + 1] + ls[(128 + c2) * 2 + 1] + ls[(192 + c2) * 2 + 1];
        pool[g * 128 + c2 * 2]     = ox;
        pool[g * 128 + c2 * 2 + 1] = oy;
    }
}

// ---------------- final: layer-2 matmuls at graph level + MLP + log_softmax ----------------
__global__ __launch_bounds__(128) void final_kernel(
    const float* __restrict__ pmdu, const float* __restrict__ pmuu, const float* __restrict__ pmud,
    const float* __restrict__ pu1,  const float* __restrict__ pd1,
    const int* __restrict__ bndu, const int* __restrict__ bndd,
    const float* __restrict__ Wl2_du, const float* __restrict__ bl2_du, const float* __restrict__ Wr2_du,
    const float* __restrict__ Wl2_uu, const float* __restrict__ bl2_uu, const float* __restrict__ Wr2_uu,
    const float* __restrict__ Wl2_ud, const float* __restrict__ bl2_ud, const float* __restrict__ Wr2_ud,
    const float* __restrict__ W1, const float* __restrict__ b1,
    const float* __restrict__ W2, const float* __restrict__ b2,
    float* __restrict__ out)
{
    int g = blockIdx.x, t = threadIdx.x;
    __shared__ float smdu[128], smuu[128], smud[128], su1[128], sd1[128];
    __shared__ float xrow[256], h[128], lg[2];
    float vdu = 0.f, vuu = 0.f, vud = 0.f;
    #pragma unroll
    for (int r = 0; r < REP; ++r) {
        vdu += pmdu[(size_t)r * NG * 128 + g * 128 + t];
        vuu += pmuu[(size_t)r * NG * 128 + g * 128 + t];
        vud += pmud[(size_t)r * NG * 128 + g * 128 + t];
    }
    smdu[t] = vdu;
    smuu[t] = vuu;
    smud[t] = vud;
    su1[t]  = pu1[g * 128 + t];
    sd1[t]  = pd1[g * 128 + t];
    __syncthreads();
    float ncu = (float)(bndu[g + 1] - bndu[g]);
    float ncd = (float)(bndd[g + 1] - bndd[g]);
    float cu = ncu > 1.f ? ncu : 1.f, cd = ncd > 1.f ? ncd : 1.f;
    float accu = ncu * (bl2_du[t] + bl2_uu[t]);
    float accd = ncd * bl2_ud[t];
    for (int k = 0; k < 128; ++k) {
        accu += smdu[k] * Wl2_du[k * 128 + t]
              + smuu[k] * Wl2_uu[k * 128 + t]
              + su1[k]  * (Wr2_du[k * 128 + t] + Wr2_uu[k * 128 + t]);
        accd += smud[k] * Wl2_ud[k * 128 + t]
              + sd1[k]  * Wr2_ud[k * 128 + t];
    }
    xrow[t]       = accu / cu;
    xrow[128 + t] = accd / cd;
    __syncthreads();
    float hh = b1[t];
    for (int k = 0; k < 256; ++k) hh += xrow[k] * W1[k * 128 + t];
    h[t] = fmaxf(hh, 0.f);
    __syncthreads();
    if (t < 2) {
        float l = b2[t];
        for (int k = 0; k < 128; ++k) l += h[k] * W2[k * 2 + t];
        lg[t] = l;
    }
    __syncthreads();
    if (t == 0) {
        float m = fmaxf(lg[0], lg[1]);
        float lse = m + logf(expf(lg[0] - m) + expf(lg[1] - m));
        out[g * 2 + 0] = lg[0] - lse;
        out[g * 2 + 1] = lg[1] - lse;
    }
}

extern "C" void kernel_launch(void* const* d_in, const int* in_sizes, int n_in,
                              void* d_out, int out_size, void* d_ws, size_t ws_size,
                              hipStream_t stream)
{
    const float* x_user = (const float*)d_in[0];
    const float* x_drug = (const float*)d_in[1];
    const int* ei_ud = (const int*)d_in[2];
    const int* ei_du = (const int*)d_in[3];
    const int* ei_uu = (const int*)d_in[4];
    const int* batch_u = (const int*)d_in[5];
    const int* batch_d = (const int*)d_in[6];
    const float* Wl1_ud = (const float*)d_in[7];  const float* bl1_ud = (const float*)d_in[8];  const float* Wr1_ud = (const float*)d_in[9];
    const float* Wl1_du = (const float*)d_in[10]; const float* bl1_du = (const float*)d_in[11]; const float* Wr1_du = (const float*)d_in[12];
    const float* Wl1_uu = (const float*)d_in[13]; const float* bl1_uu = (const float*)d_in[14]; const float* Wr1_uu = (const float*)d_in[15];
    const float* Wl2_ud = (const float*)d_in[16]; const float* bl2_ud = (const float*)d_in[17]; const float* Wr2_ud = (const float*)d_in[18];
    const float* Wl2_du = (const float*)d_in[19]; const float* bl2_du = (const float*)d_in[20]; const float* Wr2_du = (const float*)d_in[21];
    const float* Wl2_uu = (const float*)d_in[22]; const float* bl2_uu = (const float*)d_in[23]; const float* Wr2_uu = (const float*)d_in[24];
    const float* W1 = (const float*)d_in[25]; const float* b1 = (const float*)d_in[26];
    const float* W2 = (const float*)d_in[27]; const float* b2 = (const float*)d_in[28];
    (void)n_in; (void)out_size; (void)ws_size;

    const int Nu = in_sizes[0] / 128;
    const int Nd = in_sizes[1] / 128;
    const int E_ud = in_sizes[2] / 2;
    const int E_du = in_sizes[3] / 2;
    const int E_uu = in_sizes[4] / 2;
    const int nbk_u = (Nu + 63) >> 6;
    const int nbk_d = (Nd + 63) >> 6;
    const int nbk_max = nbk_u > nbk_d ? nbk_u : nbk_d;
    const int Nmax = Nu > Nd ? Nu : Nd;
    const int Emax = max(max(E_ud, E_du), E_uu);

    char* ws = (char*)d_ws;
    size_t off = 0;
    auto alloc = [&](size_t bytes) -> void* {
        void* p = ws + off;
        off = (off + bytes + 255) & ~(size_t)255;
        return p;
    };
    int2* ebuf_ud = (int2*)alloc((size_t)E_ud * 8);
    int2* ebuf_du = (int2*)alloc((size_t)E_du * 8);
    int2* ebuf_uu = (int2*)alloc((size_t)E_uu * 8);
    int* cntA_ud = (int*)alloc((size_t)NBK_MAX * GSC * 4);
    int* cntA_du = (int*)alloc((size_t)NBK_MAX * GSC * 4);
    int* cntA_uu = (int*)alloc((size_t)NBK_MAX * GSC * 4);
    int* btot_ud = (int*)alloc((size_t)NBK_MAX * 4);
    int* btot_du = (int*)alloc((size_t)NBK_MAX * 4);
    int* btot_uu = (int*)alloc((size_t)NBK_MAX * 4);
    int* bbase_ud = (int*)alloc((size_t)(NBK_MAX + 1) * 4);
    int* bbase_du = (int*)alloc((size_t)(NBK_MAX + 1) * 4);
    int* bbase_uu = (int*)alloc((size_t)(NBK_MAX + 1) * 4);
    int* csr_ud = (int*)alloc((size_t)E_ud * 4);
    int* csr_du = (int*)alloc((size_t)E_du * 4);
    int* csr_uu = (int*)alloc((size_t)E_uu * 4);
    int* rp_ud = (int*)alloc((size_t)(Nd + 1) * 4);
    int* rp_du = (int*)alloc((size_t)(Nu + 1) * 4);
    int* rp_uu = (int*)alloc((size_t)(Nu + 1) * 4);
    ushort* xb_u = (ushort*)alloc((size_t)Nu * 128 * 2);
    ushort* xb_d = (ushort*)alloc((size_t)Nd * 128 * 2);
    // layer-1 mean buffers overlay the ebufs (dead after csrify); int2 ebuf = 8B/edge >= 12.8MB each
    ushort* mean_du = (ushort*)ebuf_du;   // [Nu,128] bf16
    ushort* mean_uu = (ushort*)ebuf_uu;   // [Nu,128]
    ushort* mean_ud = (ushort*)ebuf_ud;   // [Nd,128]
    ushort* u1b = (ushort*)alloc((size_t)Nu * 128 * 2);
    ushort* d1b = (ushort*)alloc((size_t)Nd * 128 * 2);
    float* pmdu = (float*)alloc((size_t)REP * NG * 128 * 4);
    float* pmuu = (float*)alloc((size_t)REP * NG * 128 * 4);
    float* pmud = (float*)alloc((size_t)REP * NG * 128 * 4);
    char* zero2_beg = (char*)pmdu;
    char* zero2_end = ws + off;
    float* pu1  = (float*)alloc(NG * 128 * 4);
    float* pd1  = (float*)alloc(NG * 128 * 4);
    int* bnd_u = (int*)alloc((NG + 1) * 4);
    int* bnd_d = (int*)alloc((NG + 1) * 4);
    ushort* Wt_ru  = (ushort*)alloc(128 * 128 * 2);
    ushort* Wt_ldu = (ushort*)alloc(128 * 128 * 2);
    ushort* Wt_luu = (ushort*)alloc(128 * 128 * 2);
    ushort* Wt_rud = (ushort*)alloc(128 * 128 * 2);
    ushort* Wt_lud = (ushort*)alloc(128 * 128 * 2);
    float* b1s_u  = (float*)alloc(128 * 4);

    const int* dst_ud = ei_ud + E_ud;
    const int* dst_du = ei_du + E_du;
    const int* dst_uu = ei_uu + E_uu;

    // ---- CSR build via LDS bucket sort (zero device atomics), 3 types per launch ----
    bucket_count3<<<dim3(GSC, 3), 256, 0, stream>>>(
        dst_ud, E_ud, nbk_d, cntA_ud,
        dst_du, E_du, nbk_u, cntA_du,
        dst_uu, E_uu, nbk_u, cntA_uu);
    scan_blocks3<<<dim3(nbk_max, 3), GSC, 0, stream>>>(
        cntA_ud, nbk_d, btot_ud,
        cntA_du, nbk_u, btot_du,
        cntA_uu, nbk_u, btot_uu);
    scan_buckets3<<<3, 1024, 0, stream>>>(
        btot_ud, nbk_d, bbase_ud,
        btot_du, nbk_u, bbase_du,
        btot_uu, nbk_u, bbase_uu);
    bucket_scatter3<<<dim3(GSC, 3), 256, 0, stream>>>(
        ei_ud, dst_ud, E_ud, nbk_d, cntA_ud, bbase_ud, ebuf_ud,
        ei_du, dst_du, E_du, nbk_u, cntA_du, bbase_du, ebuf_du,
        ei_uu, dst_uu, E_uu, nbk_u, cntA_uu, bbase_uu, ebuf_uu);
    csrify3<<<dim3(nbk_max, 3), 256, 0, stream>>>(
        ebuf_ud, bbase_ud, Nd, E_ud, nbk_d, rp_ud, csr_ud,
        ebuf_du, bbase_du, Nu, E_du, nbk_u, rp_du, csr_du,
        ebuf_uu, bbase_uu, Nu, E_uu, nbk_u, rp_uu, csr_uu);

    // ---- graph boundaries, bf16 inputs, weight prep, pm memset ----
    bounds_kernel<<<2, NG + 1, 0, stream>>>(batch_u, Nu, batch_d, Nd, bnd_u, bnd_d);
    cvt_kernel<<<(Nu * 32 + 255) / 256, 256, 0, stream>>>(x_user, xb_u, Nu * 32);
    cvt_kernel<<<(Nd * 32 + 255) / 256, 256, 0, stream>>>(x_drug, xb_d, Nd * 32);
    wprep_kernel<<<5, 256, 0, stream>>>(Wr1_du, Wr1_uu, Wt_ru,
                                        Wl1_du, Wt_ldu, Wl1_uu, Wt_luu,
                                        Wr1_ud, Wt_rud, Wl1_ud, Wt_lud);
    add2_kernel<<<1, 128, 0, stream>>>(bl1_du, bl1_uu, b1s_u, 128);
    hipMemsetAsync(zero2_beg, 0, (size_t)(zero2_end - zero2_beg), stream);

    // ---- layer-1 aggregation (3 types, one launch; means overlay dead ebufs) ----
    agg3_kernel<<<dim3((Nmax + 3) / 4, 3), 256, 0, stream>>>(
        xb_d, rp_du, csr_du, Nu, mean_du,
        xb_u, rp_uu, csr_uu, Nu, mean_uu,
        xb_u, rp_ud, csr_ud, Nd, mean_ud);

    // ---- layer-1 MFMA GEMMs -> bf16 ----
    gemm_mfma<3><<<(Nu + 63) / 64, 256, 0, stream>>>(xb_u, mean_du, mean_uu,
                                                     Wt_ru, Wt_ldu, Wt_luu, Nu, b1s_u, u1b);
    gemm_mfma<2><<<(Nd + 63) / 64, 256, 0, stream>>>(xb_d, mean_ud, nullptr,
                                                     Wt_rud, Wt_lud, nullptr, Nd, bl1_ud, d1b);

    // ---- layer 2: fused CSR-mean + per-graph pool (4 rows/wave, replicated, one launch) ----
    aggpool3_kernel<<<dim3((Nmax + 15) / 16, 3), 256, 0, stream>>>(
        d1b, rp_du, csr_du, batch_u, Nu, pmdu,
        u1b, rp_uu, csr_uu, batch_u, Nu, pmuu,
        u1b, rp_ud, csr_ud, batch_d, Nd, pmud);

    // ---- root-term pools (direct store) ----
    pool2_kernel<<<dim3(NG, 2), 256, 0, stream>>>(u1b, d1b, bnd_u, bnd_d, pu1, pd1);

    // ---- graph-level layer-2 matmuls + MLP + log_softmax ----
    final_kernel<<<NG, 128, 0, stream>>>(pmdu, pmuu, pmud, pu1, pd1, bnd_u, bnd_d,
                                         Wl2_du, bl2_du, Wr2_du,
                                         Wl2_uu, bl2_uu, Wr2_uu,
                                         Wl2_ud, bl2_ud, Wr2_ud,
                                         W1, b1, W2, b2, (float*)d_out);
}